// Round 5
// baseline (12073.556 us; speedup 1.0000x reference)
//
#include <hip/hip_runtime.h>
#include <stdint.h>

#define N_NODES 100000
#define N_EDGES 1600000
#define HDIM    128
#define KSTEPS  10
#define NZONE   8                 // dst classes for atomic-free fill
#define ZDIV    12500u

// ---- src-zone-major CSR: bin = (src/SZDIV)*N + dst ----
#define NZS     8                 // src zones (3.2 MB of uin each ~ one XCD L2)
#define SZDIV   12500u
#define NBINS   (NZS * N_NODES)   // 800K bins

// ---- step kernel geometry ----
#define JPW     16                // nodes per wave (j packed in col bits 20..23)
#define NWV     4                 // waves per block

typedef unsigned int uint;

// ---- CSR-build scan config ----
#define SCAN_T     256
#define SCAN_I     4
#define SCAN_ELEMS (SCAN_T * SCAN_I)                        // 1024
#define SCAN_NB    ((NBINS + SCAN_ELEMS - 1) / SCAN_ELEMS)  // 782
#define S2_I       4                                        // 256*4 >= 782

// ---- bf16x2 helpers (RNE) ----
__device__ inline float2 bf2_to_f2(uint v) {
    float2 r;
    r.x = __uint_as_float(v << 16);
    r.y = __uint_as_float(v & 0xffff0000u);
    return r;
}
__device__ inline uint f_to_bf_bits(float f) {
    uint u = __float_as_uint(f);
    return (u + 0x7fffu + ((u >> 16) & 1u)) >> 16;
}
__device__ inline uint f2_to_bf2(float x, float y) {
    return f_to_bf_bits(x) | (f_to_bf_bits(y) << 16);
}

// ------- fused degree-count + in-bin position (one atomic pass) -------
__global__ void k_countpos(const int* __restrict__ eidx, int* __restrict__ cnt,
                           int* __restrict__ pos) {
    int e0 = (blockIdx.x * blockDim.x + threadIdx.x) * 4;
    if (e0 < N_EDGES) {
        int4 s4 = *(const int4*)&eidx[e0];
        int4 d4 = *(const int4*)&eidx[N_EDGES + e0];
        int4 p;
        p.x = atomicAdd(&cnt[(int)((uint)s4.x / SZDIV) * N_NODES + d4.x], 1);
        p.y = atomicAdd(&cnt[(int)((uint)s4.y / SZDIV) * N_NODES + d4.y], 1);
        p.z = atomicAdd(&cnt[(int)((uint)s4.z / SZDIV) * N_NODES + d4.z], 1);
        p.w = atomicAdd(&cnt[(int)((uint)s4.w / SZDIV) * N_NODES + d4.w], 1);
        *(int4*)&pos[e0] = p;
    }
}

// ---------------- exclusive scan over NBINS (3-phase) ----------------
__global__ void k_scan1(const int* __restrict__ cnt, int* __restrict__ rp,
                        int* __restrict__ bsum) {
    __shared__ int s[SCAN_T];
    int tid  = threadIdx.x;
    int base = blockIdx.x * SCAN_ELEMS + tid * SCAN_I;
    int v[SCAN_I];
    int loc = 0;
#pragma unroll
    for (int j = 0; j < SCAN_I; ++j) {
        int idx = base + j;
        v[j] = (idx < NBINS) ? cnt[idx] : 0;
        loc += v[j];
    }
    s[tid] = loc;
    __syncthreads();
    for (int off = 1; off < SCAN_T; off <<= 1) {
        int t = (tid >= off) ? s[tid - off] : 0;
        __syncthreads();
        s[tid] += t;
        __syncthreads();
    }
    int run = s[tid] - loc;
#pragma unroll
    for (int j = 0; j < SCAN_I; ++j) {
        int idx = base + j;
        if (idx < NBINS) rp[idx] = run;
        run += v[j];
    }
    if (tid == SCAN_T - 1) bsum[blockIdx.x] = s[SCAN_T - 1];
}

__global__ void k_scan2(const int* __restrict__ bsum, int* __restrict__ boff,
                        int* __restrict__ rp) {
    __shared__ int s[SCAN_T];
    int tid = threadIdx.x;
    int v[S2_I];
    int loc = 0;
#pragma unroll
    for (int j = 0; j < S2_I; ++j) {
        int idx = tid * S2_I + j;
        v[j] = (idx < SCAN_NB) ? bsum[idx] : 0;
        loc += v[j];
    }
    s[tid] = loc;
    __syncthreads();
    for (int off = 1; off < SCAN_T; off <<= 1) {
        int t = (tid >= off) ? s[tid - off] : 0;
        __syncthreads();
        s[tid] += t;
        __syncthreads();
    }
    int run = s[tid] - loc;
#pragma unroll
    for (int j = 0; j < S2_I; ++j) {
        int idx = tid * S2_I + j;
        if (idx < SCAN_NB) boff[idx] = run;
        run += v[j];
    }
    if (tid == SCAN_T - 1) rp[NBINS] = s[SCAN_T - 1];
}

__global__ void k_scan3(int* __restrict__ rp, const int* __restrict__ boff) {
    int off = boff[blockIdx.x];
#pragma unroll
    for (int j = 0; j < SCAN_I; ++j) {
        int i = blockIdx.x * SCAN_ELEMS + threadIdx.x + j * SCAN_T;
        if (i < NBINS) rp[i] += off;
    }
}

// -------- dinv = rsqrt(1+deg), dsq = sqrt(1+deg); deg from zone-major rpz --------
__global__ void k_dinv(const int* __restrict__ rpz, float* __restrict__ dinv,
                       float* __restrict__ dsq) {
    int i = blockIdx.x * blockDim.x + threadIdx.x;
    if (i < N_NODES) {
        int deg = 0;
#pragma unroll
        for (int z = 0; z < NZS; ++z)
            deg += rpz[(size_t)z * N_NODES + i + 1] - rpz[(size_t)z * N_NODES + i];
        float d = 1.0f + (float)deg;
        dinv[i] = rsqrtf(d);
        dsq[i]  = sqrtf(d);
    }
}

// ------- dst-class-partitioned, atomic-free CSR fill; packs j=dst&15 in col -------
#define FCHUNK 8192
#define FECH   ((N_EDGES + FCHUNK - 1) / FCHUNK)
__global__ __launch_bounds__(256)
void k_fill2(const int* __restrict__ eidx, const int* __restrict__ rpz,
             const int* __restrict__ pos, uint* __restrict__ col) {
    uint zone = blockIdx.x;
    int  base = blockIdx.y * FCHUNK;
#pragma unroll
    for (int i = 0; i < FCHUNK / 1024; ++i) {
        int e0 = base + (i * 256 + (int)threadIdx.x) * 4;
        if (e0 < N_EDGES) {
            int4 d4 = *(const int4*)&eidx[N_EDGES + e0];
            int4 s4 = *(const int4*)&eidx[e0];
            int4 p4 = *(const int4*)&pos[e0];
            if ((uint)d4.x / ZDIV == zone)
                col[rpz[(int)((uint)s4.x / SZDIV) * N_NODES + d4.x] + p4.x] =
                    (uint)s4.x | ((uint)(d4.x & (JPW - 1)) << 20);
            if ((uint)d4.y / ZDIV == zone)
                col[rpz[(int)((uint)s4.y / SZDIV) * N_NODES + d4.y] + p4.y] =
                    (uint)s4.y | ((uint)(d4.y & (JPW - 1)) << 20);
            if ((uint)d4.z / ZDIV == zone)
                col[rpz[(int)((uint)s4.z / SZDIV) * N_NODES + d4.z] + p4.z] =
                    (uint)s4.z | ((uint)(d4.z & (JPW - 1)) << 20);
            if ((uint)d4.w / ZDIV == zone)
                col[rpz[(int)((uint)s4.w / SZDIV) * N_NODES + d4.w] + p4.w] =
                    (uint)s4.w | ((uint)(d4.w & (JPW - 1)) << 20);
        }
    }
}

// ---------------- GEMM1: u0 = bf16( dinv * relu(x @ W1 + b1) ) ----------------
#define KCH 64
__global__ __launch_bounds__(256)
void k_gemm1(const float* __restrict__ x, const float* __restrict__ W,
             const float* __restrict__ bias, const float* __restrict__ dinv,
             uint* __restrict__ out) {
    __shared__ __align__(16) float wlds[KCH][HDIM];
    __shared__ __align__(16) float xs[32][KCH + 1];
    int tid  = threadIdx.x;
    int tx   = tid & 31, ty = tid >> 5;
    int row0 = blockIdx.x * 32;

    float4 bc = *(const float4*)&bias[tx * 4];

    float acc[4][4] = {};
    for (int kc = 0; kc < HDIM; kc += KCH) {
#pragma unroll
        for (int i = 0; i < 8; ++i) {
            int id = tid + i * 256;
            int kk = id >> 5, n4 = id & 31;
            *(float4*)&wlds[kk][n4 * 4] =
                *(const float4*)&W[(size_t)(kc + kk) * HDIM + n4 * 4];
        }
#pragma unroll
        for (int i = 0; i < 2; ++i) {
            int id = tid + i * 256;
            int r = id >> 4, c4 = id & 15;
            float4 v = *(const float4*)&x[(size_t)(row0 + r) * HDIM + kc + c4 * 4];
            xs[r][c4 * 4 + 0] = v.x;
            xs[r][c4 * 4 + 1] = v.y;
            xs[r][c4 * 4 + 2] = v.z;
            xs[r][c4 * 4 + 3] = v.w;
        }
        __syncthreads();
#pragma unroll 8
        for (int kk = 0; kk < KCH; ++kk) {
            float4 b4 = *(const float4*)&wlds[kk][tx * 4];
            float a0 = xs[ty * 4 + 0][kk];
            float a1 = xs[ty * 4 + 1][kk];
            float a2 = xs[ty * 4 + 2][kk];
            float a3 = xs[ty * 4 + 3][kk];
            acc[0][0] += a0 * b4.x; acc[0][1] += a0 * b4.y; acc[0][2] += a0 * b4.z; acc[0][3] += a0 * b4.w;
            acc[1][0] += a1 * b4.x; acc[1][1] += a1 * b4.y; acc[1][2] += a1 * b4.z; acc[1][3] += a1 * b4.w;
            acc[2][0] += a2 * b4.x; acc[2][1] += a2 * b4.y; acc[2][2] += a2 * b4.z; acc[2][3] += a2 * b4.w;
            acc[3][0] += a3 * b4.x; acc[3][1] += a3 * b4.y; acc[3][2] += a3 * b4.z; acc[3][3] += a3 * b4.w;
        }
        __syncthreads();
    }
#pragma unroll
    for (int r = 0; r < 4; ++r) {
        int row = row0 + ty * 4 + r;
        float di = dinv[row];
        float v0 = fmaxf(acc[r][0] + bc.x, 0.0f) * di;
        float v1 = fmaxf(acc[r][1] + bc.y, 0.0f) * di;
        float v2 = fmaxf(acc[r][2] + bc.z, 0.0f) * di;
        float v3 = fmaxf(acc[r][3] + bc.w, 0.0f) * di;
        uint2 p;
        p.x = f2_to_bf2(v0, v1);
        p.y = f2_to_bf2(v2, v3);
        *(uint2*)&out[(size_t)row * 64 + tx * 2] = p;
    }
}

// ---------------- GEMM2: out = (dsq * bf16 u) @ W2 + b2, fp32 out ----------------
__global__ __launch_bounds__(256)
void k_gemm2(const uint* __restrict__ u, const float* __restrict__ W,
             const float* __restrict__ bias, const float* __restrict__ dsq,
             float* __restrict__ out) {
    __shared__ __align__(16) float wlds[KCH][HDIM];
    __shared__ __align__(16) float xs[32][KCH + 1];
    int tid  = threadIdx.x;
    int tx   = tid & 31, ty = tid >> 5;
    int row0 = blockIdx.x * 32;

    float4 bc = *(const float4*)&bias[tx * 4];

    float acc[4][4] = {};
    for (int kc = 0; kc < HDIM; kc += KCH) {
#pragma unroll
        for (int i = 0; i < 8; ++i) {
            int id = tid + i * 256;
            int kk = id >> 5, n4 = id & 31;
            *(float4*)&wlds[kk][n4 * 4] =
                *(const float4*)&W[(size_t)(kc + kk) * HDIM + n4 * 4];
        }
#pragma unroll
        for (int i = 0; i < 2; ++i) {
            int id = tid + i * 256;
            int r = id >> 4, c4 = id & 15;
            float ds = dsq[row0 + r];
            uint2 v = *(const uint2*)&u[(size_t)(row0 + r) * 64 + (kc >> 1) + c4 * 2];
            float2 f0 = bf2_to_f2(v.x);
            float2 f1 = bf2_to_f2(v.y);
            xs[r][c4 * 4 + 0] = f0.x * ds;
            xs[r][c4 * 4 + 1] = f0.y * ds;
            xs[r][c4 * 4 + 2] = f1.x * ds;
            xs[r][c4 * 4 + 3] = f1.y * ds;
        }
        __syncthreads();
#pragma unroll 8
        for (int kk = 0; kk < KCH; ++kk) {
            float4 b4 = *(const float4*)&wlds[kk][tx * 4];
            float a0 = xs[ty * 4 + 0][kk];
            float a1 = xs[ty * 4 + 1][kk];
            float a2 = xs[ty * 4 + 2][kk];
            float a3 = xs[ty * 4 + 3][kk];
            acc[0][0] += a0 * b4.x; acc[0][1] += a0 * b4.y; acc[0][2] += a0 * b4.z; acc[0][3] += a0 * b4.w;
            acc[1][0] += a1 * b4.x; acc[1][1] += a1 * b4.y; acc[1][2] += a1 * b4.z; acc[1][3] += a1 * b4.w;
            acc[2][0] += a2 * b4.x; acc[2][1] += a2 * b4.y; acc[2][2] += a2 * b4.z; acc[2][3] += a2 * b4.w;
            acc[3][0] += a3 * b4.x; acc[3][1] += a3 * b4.y; acc[3][2] += a3 * b4.z; acc[3][3] += a3 * b4.w;
        }
        __syncthreads();
    }
#pragma unroll
    for (int r = 0; r < 4; ++r) {
        int row = row0 + ty * 4 + r;
        float4 v;
        v.x = acc[r][0] + bc.x;
        v.y = acc[r][1] + bc.y;
        v.z = acc[r][2] + bc.z;
        v.w = acc[r][3] + bc.w;
        *(float4*)&out[(size_t)row * HDIM + tx * 4] = v;
    }
}

// ---- APPNP step: zone-phased sweep + native ds_add_f32 LDS accumulation ----
// Wave owns JPW=16 nodes; per src zone its edges are contiguous
// [rpz[z*N+n0], rpz[z*N+n0+16]); col packs src | (dst&15)<<20.
// ds_add_f32 is fire-and-forget (no return, no CAS loop, no register dep):
// gathers pipeline 8-deep exactly like the dense round-0 kernel.
// lacc layout [j][plane][lane]: ds addr = base + j*512 + plane*256 + lane*4
// -> bank = lane%32, 2 lanes/bank = conflict-free.
#define ACC(c, g) do {                                                     \
        uint a_ = Ax + (((c) >> 11) & 0x1E00u);          /* + j*512 */     \
        asm volatile("ds_add_f32 %0, %1"                                   \
                     :: "v"(a_), "v"(__uint_as_float((g) << 16)));         \
        asm volatile("ds_add_f32 %0, %1 offset:256"                        \
                     :: "v"(a_), "v"(__uint_as_float((g) & 0xffff0000u))); \
    } while (0)

__global__ __launch_bounds__(256)
void k_prop(const uint* __restrict__ uin, const uint* __restrict__ u0,
            uint* __restrict__ uout, const uint* __restrict__ colp,
            const int* __restrict__ rpz, const float* __restrict__ dinv) {
    __shared__ float lacc[NWV][JPW][2][64];                   // 32 KB
    int lane = threadIdx.x & 63;
    int warp = __builtin_amdgcn_readfirstlane((int)(threadIdx.x >> 6));
    int wid  = blockIdx.x * NWV + warp;
    int n0   = wid * JPW;
    float* A = &lacc[warp][0][0][0];

    // zero wave-private accumulators (2048 floats)
    float4 z4 = {0.f, 0.f, 0.f, 0.f};
#pragma unroll
    for (int i = 0; i < 8; ++i)
        *(float4*)&A[(i * 64 + lane) * 4] = z4;
    __syncthreads();   // fence zero-stores before the ds_add asms

    // LDS byte address of this lane's x-plane slot for j=0
    uint Ax = (uint)(uintptr_t)&lacc[warp][0][0][lane];

    if (n0 < N_NODES) {
        for (int z = 0; z < NZS; ++z) {
            int b0 = rpz[z * N_NODES + n0];
            int b1 = rpz[z * N_NODES + n0 + JPW];
            int e = b0;
            for (; e + 8 <= b1; e += 8) {
                uint c0 = colp[e + 0], c1 = colp[e + 1];
                uint c2 = colp[e + 2], c3 = colp[e + 3];
                uint c4 = colp[e + 4], c5 = colp[e + 5];
                uint c6 = colp[e + 6], c7 = colp[e + 7];
                uint g0 = uin[(size_t)(c0 & 0xFFFFFu) * 64 + lane];
                uint g1 = uin[(size_t)(c1 & 0xFFFFFu) * 64 + lane];
                uint g2 = uin[(size_t)(c2 & 0xFFFFFu) * 64 + lane];
                uint g3 = uin[(size_t)(c3 & 0xFFFFFu) * 64 + lane];
                uint g4 = uin[(size_t)(c4 & 0xFFFFFu) * 64 + lane];
                uint g5 = uin[(size_t)(c5 & 0xFFFFFu) * 64 + lane];
                uint g6 = uin[(size_t)(c6 & 0xFFFFFu) * 64 + lane];
                uint g7 = uin[(size_t)(c7 & 0xFFFFFu) * 64 + lane];
                ACC(c0, g0); ACC(c1, g1); ACC(c2, g2); ACC(c3, g3);
                ACC(c4, g4); ACC(c5, g5); ACC(c6, g6); ACC(c7, g7);
            }
            if (e + 4 <= b1) {
                uint c0 = colp[e + 0], c1 = colp[e + 1];
                uint c2 = colp[e + 2], c3 = colp[e + 3];
                uint g0 = uin[(size_t)(c0 & 0xFFFFFu) * 64 + lane];
                uint g1 = uin[(size_t)(c1 & 0xFFFFFu) * 64 + lane];
                uint g2 = uin[(size_t)(c2 & 0xFFFFFu) * 64 + lane];
                uint g3 = uin[(size_t)(c3 & 0xFFFFFu) * 64 + lane];
                ACC(c0, g0); ACC(c1, g1); ACC(c2, g2); ACC(c3, g3);
                e += 4;
            }
            if (e + 2 <= b1) {
                uint c0 = colp[e + 0], c1 = colp[e + 1];
                uint g0 = uin[(size_t)(c0 & 0xFFFFFu) * 64 + lane];
                uint g1 = uin[(size_t)(c1 & 0xFFFFFu) * 64 + lane];
                ACC(c0, g0); ACC(c1, g1);
                e += 2;
            }
            if (e < b1) {
                uint c0 = colp[e];
                uint g0 = uin[(size_t)(c0 & 0xFFFFFu) * 64 + lane];
                ACC(c0, g0);
            }
        }
    }
    __syncthreads();   // drain ds_adds; fence before epilogue LDS reads

    if (n0 < N_NODES) {
        // epilogue: u' = 0.9*dinv^2*(acc + self) + 0.1*u0
#pragma unroll 4
        for (int j = 0; j < JPW; ++j) {
            int n = n0 + j;
            size_t self = (size_t)n * 64 + lane;
            uint usv = uin[self];
            uint uzv = __builtin_nontemporal_load(&u0[self]);
            float di = dinv[n];
            float w  = 0.9f * di * di;
            float sx = lacc[warp][j][0][lane];
            float sy = lacc[warp][j][1][lane];
            float2 us = bf2_to_f2(usv);
            float2 uz = bf2_to_f2(uzv);
            float ox = w * (sx + us.x) + 0.1f * uz.x;
            float oy = w * (sy + us.y) + 0.1f * uz.y;
            __builtin_nontemporal_store(f2_to_bf2(ox, oy), &uout[self]);
        }
    }
}

extern "C" void kernel_launch(void* const* d_in, const int* in_sizes, int n_in,
                              void* d_out, int out_size, void* d_ws, size_t ws_size,
                              hipStream_t stream) {
    (void)in_sizes; (void)n_in; (void)out_size; (void)ws_size;
    const float* x  = (const float*)d_in[0];
    const int*   ei = (const int*)d_in[1];
    const float* W1 = (const float*)d_in[2];
    const float* b1 = (const float*)d_in[3];
    const float* W2 = (const float*)d_in[4];
    const float* b2 = (const float*)d_in[5];
    float* out = (float*)d_out;

    char* ws = (char*)d_ws;
    size_t off = 0;
    auto alloc = [&](size_t bytes) -> void* {
        void* p = ws + off;
        off += (bytes + 255) & ~(size_t)255;
        return p;
    };
    uint*  u0   = (uint*)alloc(sizeof(uint) * (size_t)N_NODES * 64);
    uint*  uA   = (uint*)alloc(sizeof(uint) * (size_t)N_NODES * 64);
    uint*  uB   = (uint*)alloc(sizeof(uint) * (size_t)N_NODES * 64);
    uint*  col  = (uint*)alloc(sizeof(uint) * (N_EDGES + 64));
    int*   rpz  = (int*)alloc(sizeof(int) * (NBINS + 1));
    float* dinv = (float*)alloc(sizeof(float) * N_NODES);
    float* dsq  = (float*)alloc(sizeof(float) * N_NODES);
    int*   bsum = (int*)alloc(sizeof(int) * SCAN_NB);
    int*   boff = (int*)alloc(sizeof(int) * SCAN_NB);
    // cnt dead after k_scan1 (uA first written as uout at step k=0, after fill);
    // pos dead after k_fill2 (uB first written at step k=1).
    int*   cnt  = (int*)uA;
    int*   pos  = (int*)uB;

    hipMemsetAsync(cnt, 0, sizeof(int) * NBINS, stream);

    k_countpos<<<(N_EDGES / 4 + 255) / 256, 256, 0, stream>>>(ei, cnt, pos);
    k_scan1<<<SCAN_NB, SCAN_T, 0, stream>>>(cnt, rpz, bsum);
    k_scan2<<<1, SCAN_T, 0, stream>>>(bsum, boff, rpz);
    k_scan3<<<SCAN_NB, SCAN_T, 0, stream>>>(rpz, boff);
    k_dinv<<<(N_NODES + 255) / 256, 256, 0, stream>>>(rpz, dinv, dsq);
    {
        dim3 g(NZONE, FECH);
        k_fill2<<<g, 256, 0, stream>>>(ei, rpz, pos, col);
    }

    k_gemm1<<<N_NODES / 32, 256, 0, stream>>>(x, W1, b1, dinv, u0);

    const uint* uin = u0;
    uint* uout = uA;
    int nblk = (N_NODES / JPW + NWV - 1) / NWV;   // 1563
    for (int k = 0; k < KSTEPS; ++k) {
        k_prop<<<nblk, 256, 0, stream>>>(uin, u0, uout, col, rpz, dinv);
        uin = uout;
        uout = (uout == uA) ? uB : uA;
    }
    k_gemm2<<<N_NODES / 32, 256, 0, stream>>>(uin, W2, b2, dsq, out);
}

// Round 7
// 929.810 us; speedup vs baseline: 12.9850x; 12.9850x over previous
//
#include <hip/hip_runtime.h>
#include <stdint.h>

#define N_NODES 100000
#define N_EDGES 1600000
#define HDIM    128
#define KSTEPS  10
#define NZONE   8
#define ZDIV    12500u            // N_NODES / NZONE

typedef unsigned int uint;
typedef int iv4 __attribute__((ext_vector_type(4)));   // native vec for nt builtins

// ---- CSR-build scan config ----
#define SCAN_T     256
#define SCAN_I     4
#define SCAN_ELEMS (SCAN_T * SCAN_I)                         // 1024
#define SCAN_NB    ((N_NODES + SCAN_ELEMS - 1) / SCAN_ELEMS) // 98

// ---- bf16x2 helpers (RNE) ----
__device__ inline float2 bf2_to_f2(uint v) {
    float2 r;
    r.x = __uint_as_float(v << 16);
    r.y = __uint_as_float(v & 0xffff0000u);
    return r;
}
__device__ inline uint f_to_bf_bits(float f) {        // returns bf16 in low 16
    uint u = __float_as_uint(f);
    return (u + 0x7fffu + ((u >> 16) & 1u)) >> 16;
}
__device__ inline uint f2_to_bf2(float x, float y) {
    return f_to_bf_bits(x) | (f_to_bf_bits(y) << 16);
}

// ------- fused degree-count + in-bucket position (one atomic pass) -------
// edges are streamed once -> nt loads; pos written once, read once -> nt store
__global__ void k_countpos(const int* __restrict__ eidx, int* __restrict__ cnt,
                           int* __restrict__ pos) {
    int e0 = (blockIdx.x * blockDim.x + threadIdx.x) * 4;
    if (e0 < N_EDGES) {
        iv4 d4 = __builtin_nontemporal_load((const iv4*)&eidx[N_EDGES + e0]);
        iv4 p;
        p.x = atomicAdd(&cnt[d4.x], 1);
        p.y = atomicAdd(&cnt[d4.y], 1);
        p.z = atomicAdd(&cnt[d4.z], 1);
        p.w = atomicAdd(&cnt[d4.w], 1);
        __builtin_nontemporal_store(p, (iv4*)&pos[e0]);
    }
}

// ----- exclusive scan phase 1, fused with dinv/dsq (cnt is read here anyway) -----
__global__ void k_scan1(const int* __restrict__ cnt, int* __restrict__ rp,
                        int* __restrict__ bsum, float* __restrict__ dinv,
                        float* __restrict__ dsq) {
    __shared__ int s[SCAN_T];
    int tid  = threadIdx.x;
    int base = blockIdx.x * SCAN_ELEMS + tid * SCAN_I;
    int v[SCAN_I];
    int loc = 0;
#pragma unroll
    for (int j = 0; j < SCAN_I; ++j) {
        int idx = base + j;
        v[j] = (idx < N_NODES) ? cnt[idx] : 0;
        loc += v[j];
    }
    // fused: dinv = rsqrt(1+deg), dsq = sqrt(1+deg)  (self loop included)
#pragma unroll
    for (int j = 0; j < SCAN_I; ++j) {
        int idx = base + j;
        if (idx < N_NODES) {
            float d = 1.0f + (float)v[j];
            dinv[idx] = rsqrtf(d);
            dsq[idx]  = sqrtf(d);
        }
    }
    s[tid] = loc;
    __syncthreads();
    for (int off = 1; off < SCAN_T; off <<= 1) {
        int t = (tid >= off) ? s[tid - off] : 0;
        __syncthreads();
        s[tid] += t;
        __syncthreads();
    }
    int run = s[tid] - loc;   // exclusive prefix for this thread
#pragma unroll
    for (int j = 0; j < SCAN_I; ++j) {
        int idx = base + j;
        if (idx < N_NODES) rp[idx] = run;
        run += v[j];
    }
    if (tid == SCAN_T - 1) bsum[blockIdx.x] = s[SCAN_T - 1];
}

// parallel block-sum scan (98 elems, one element per thread)
__global__ void k_scan2(const int* __restrict__ bsum, int* __restrict__ boff,
                        int* __restrict__ rp) {
    __shared__ int s[SCAN_T];
    int tid = threadIdx.x;
    int v = (tid < SCAN_NB) ? bsum[tid] : 0;
    s[tid] = v;
    __syncthreads();
    for (int off = 1; off < SCAN_T; off <<= 1) {
        int t = (tid >= off) ? s[tid - off] : 0;
        __syncthreads();
        s[tid] += t;
        __syncthreads();
    }
    if (tid < SCAN_NB) boff[tid] = s[tid] - v;      // exclusive
    if (tid == SCAN_T - 1) rp[N_NODES] = s[SCAN_T - 1];
}

__global__ void k_scan3(int* __restrict__ rp, const int* __restrict__ boff) {
    int off = boff[blockIdx.x];
#pragma unroll
    for (int j = 0; j < SCAN_I; ++j) {
        int i = blockIdx.x * SCAN_ELEMS + threadIdx.x + j * SCAN_T;
        if (i < N_NODES) rp[i] += off;
    }
}

// ------- zone-partitioned CSR fill, atomic-free -------
// grid = (NZONE, FECH); linear block id = z + NZONE*c -> blocks of one zone land
// on one XCD (round-robin heuristic) -> col lines for a zone dirty one L2 only.
#define FCHUNK 8192
#define FECH   ((N_EDGES + FCHUNK - 1) / FCHUNK)
__global__ __launch_bounds__(256)
void k_fill2(const int* __restrict__ eidx, const int* __restrict__ rp,
             const int* __restrict__ pos, int* __restrict__ col) {
    uint zone = blockIdx.x;
    int  base = blockIdx.y * FCHUNK;
#pragma unroll
    for (int i = 0; i < FCHUNK / 1024; ++i) {     // 8 iters x 1024 edges/block
        int e0 = base + (i * 256 + (int)threadIdx.x) * 4;
        if (e0 < N_EDGES) {
            iv4 d4 = __builtin_nontemporal_load((const iv4*)&eidx[N_EDGES + e0]);
            iv4 s4 = __builtin_nontemporal_load((const iv4*)&eidx[e0]);
            iv4 p4 = __builtin_nontemporal_load((const iv4*)&pos[e0]);
            if ((uint)d4.x / ZDIV == zone) col[rp[d4.x] + p4.x] = s4.x;
            if ((uint)d4.y / ZDIV == zone) col[rp[d4.y] + p4.y] = s4.y;
            if ((uint)d4.z / ZDIV == zone) col[rp[d4.z] + p4.z] = s4.z;
            if ((uint)d4.w / ZDIV == zone) col[rp[d4.w] + p4.w] = s4.w;
        }
    }
}

// ---------------- GEMM1: u0 = bf16( dinv * relu(x @ W1 + b1) ) ----------------
#define KCH 64
__global__ __launch_bounds__(256)
void k_gemm1(const float* __restrict__ x, const float* __restrict__ W,
             const float* __restrict__ bias, const float* __restrict__ dinv,
             uint* __restrict__ out) {
    __shared__ __align__(16) float wlds[KCH][HDIM];     // 32 KB
    __shared__ __align__(16) float xs[32][KCH + 1];     // ~8.3 KB
    int tid  = threadIdx.x;
    int tx   = tid & 31, ty = tid >> 5;
    int row0 = blockIdx.x * 32;

    float4 bc = *(const float4*)&bias[tx * 4];

    float acc[4][4] = {};
    for (int kc = 0; kc < HDIM; kc += KCH) {
#pragma unroll
        for (int i = 0; i < 8; ++i) {
            int id = tid + i * 256;
            int kk = id >> 5, n4 = id & 31;
            *(float4*)&wlds[kk][n4 * 4] =
                *(const float4*)&W[(size_t)(kc + kk) * HDIM + n4 * 4];
        }
#pragma unroll
        for (int i = 0; i < 2; ++i) {
            int id = tid + i * 256;
            int r = id >> 4, c4 = id & 15;
            float4 v = *(const float4*)&x[(size_t)(row0 + r) * HDIM + kc + c4 * 4];
            xs[r][c4 * 4 + 0] = v.x;
            xs[r][c4 * 4 + 1] = v.y;
            xs[r][c4 * 4 + 2] = v.z;
            xs[r][c4 * 4 + 3] = v.w;
        }
        __syncthreads();
#pragma unroll 8
        for (int kk = 0; kk < KCH; ++kk) {
            float4 b4 = *(const float4*)&wlds[kk][tx * 4];
            float a0 = xs[ty * 4 + 0][kk];
            float a1 = xs[ty * 4 + 1][kk];
            float a2 = xs[ty * 4 + 2][kk];
            float a3 = xs[ty * 4 + 3][kk];
            acc[0][0] += a0 * b4.x; acc[0][1] += a0 * b4.y; acc[0][2] += a0 * b4.z; acc[0][3] += a0 * b4.w;
            acc[1][0] += a1 * b4.x; acc[1][1] += a1 * b4.y; acc[1][2] += a1 * b4.z; acc[1][3] += a1 * b4.w;
            acc[2][0] += a2 * b4.x; acc[2][1] += a2 * b4.y; acc[2][2] += a2 * b4.z; acc[2][3] += a2 * b4.w;
            acc[3][0] += a3 * b4.x; acc[3][1] += a3 * b4.y; acc[3][2] += a3 * b4.z; acc[3][3] += a3 * b4.w;
        }
        __syncthreads();
    }
#pragma unroll
    for (int r = 0; r < 4; ++r) {
        int row = row0 + ty * 4 + r;
        float di = dinv[row];
        float v0 = fmaxf(acc[r][0] + bc.x, 0.0f) * di;
        float v1 = fmaxf(acc[r][1] + bc.y, 0.0f) * di;
        float v2 = fmaxf(acc[r][2] + bc.z, 0.0f) * di;
        float v3 = fmaxf(acc[r][3] + bc.w, 0.0f) * di;
        uint2 p;
        p.x = f2_to_bf2(v0, v1);
        p.y = f2_to_bf2(v2, v3);
        *(uint2*)&out[(size_t)row * 64 + tx * 2] = p;   // row = 64 uints (128 bf16)
    }
}

// ---------------- GEMM2: out = (dsq * bf16 u) @ W2 + b2, fp32 out ----------------
__global__ __launch_bounds__(256)
void k_gemm2(const uint* __restrict__ u, const float* __restrict__ W,
             const float* __restrict__ bias, const float* __restrict__ dsq,
             float* __restrict__ out) {
    __shared__ __align__(16) float wlds[KCH][HDIM];
    __shared__ __align__(16) float xs[32][KCH + 1];
    int tid  = threadIdx.x;
    int tx   = tid & 31, ty = tid >> 5;
    int row0 = blockIdx.x * 32;

    float4 bc = *(const float4*)&bias[tx * 4];

    float acc[4][4] = {};
    for (int kc = 0; kc < HDIM; kc += KCH) {
#pragma unroll
        for (int i = 0; i < 8; ++i) {
            int id = tid + i * 256;
            int kk = id >> 5, n4 = id & 31;
            *(float4*)&wlds[kk][n4 * 4] =
                *(const float4*)&W[(size_t)(kc + kk) * HDIM + n4 * 4];
        }
#pragma unroll
        for (int i = 0; i < 2; ++i) {
            int id = tid + i * 256;
            int r = id >> 4, c4 = id & 15;
            float ds = dsq[row0 + r];
            uint2 v = *(const uint2*)&u[(size_t)(row0 + r) * 64 + (kc >> 1) + c4 * 2];
            float2 f0 = bf2_to_f2(v.x);
            float2 f1 = bf2_to_f2(v.y);
            xs[r][c4 * 4 + 0] = f0.x * ds;
            xs[r][c4 * 4 + 1] = f0.y * ds;
            xs[r][c4 * 4 + 2] = f1.x * ds;
            xs[r][c4 * 4 + 3] = f1.y * ds;
        }
        __syncthreads();
#pragma unroll 8
        for (int kk = 0; kk < KCH; ++kk) {
            float4 b4 = *(const float4*)&wlds[kk][tx * 4];
            float a0 = xs[ty * 4 + 0][kk];
            float a1 = xs[ty * 4 + 1][kk];
            float a2 = xs[ty * 4 + 2][kk];
            float a3 = xs[ty * 4 + 3][kk];
            acc[0][0] += a0 * b4.x; acc[0][1] += a0 * b4.y; acc[0][2] += a0 * b4.z; acc[0][3] += a0 * b4.w;
            acc[1][0] += a1 * b4.x; acc[1][1] += a1 * b4.y; acc[1][2] += a1 * b4.z; acc[1][3] += a1 * b4.w;
            acc[2][0] += a2 * b4.x; acc[2][1] += a2 * b4.y; acc[2][2] += a2 * b4.z; acc[2][3] += a2 * b4.w;
            acc[3][0] += a3 * b4.x; acc[3][1] += a3 * b4.y; acc[3][2] += a3 * b4.z; acc[3][3] += a3 * b4.w;
        }
        __syncthreads();
    }
#pragma unroll
    for (int r = 0; r < 4; ++r) {
        int row = row0 + ty * 4 + r;
        float4 v;
        v.x = acc[r][0] + bc.x;
        v.y = acc[r][1] + bc.y;
        v.z = acc[r][2] + bc.z;
        v.w = acc[r][3] + bc.w;
        *(float4*)&out[(size_t)row * HDIM + tx * 4] = v;
    }
}

// ---- APPNP step, u stored bf16x2: u' = 0.9*dinv^2*(sum u[s] + u[i]) + 0.1*u0 ----
// One wave per node; dense 8-deep gather pipeline (champion structure).
// col is streamed exactly once per step -> nt loads keep L2 free for uin rows.
__global__ __launch_bounds__(256)
void k_step(const uint* __restrict__ uin, const uint* __restrict__ u0,
            uint* __restrict__ uout, const int* __restrict__ col,
            const int* __restrict__ rp, const float* __restrict__ dinv) {
    int wid  = (blockIdx.x * blockDim.x + threadIdx.x) >> 6;
    int node = __builtin_amdgcn_readfirstlane(wid);
    int lane = threadIdx.x & 63;
    if (node >= N_NODES) return;

    size_t self = (size_t)node * 64 + lane;
    uint usv = uin[self];                              // self row (gather-hot region)
    uint uzv = __builtin_nontemporal_load(&u0[self]);  // one-touch stream
    float di = dinv[node];
    float w  = 0.9f * di * di;

    int beg = rp[node], end = rp[node + 1];
    float2 us = bf2_to_f2(usv);
    float accx = us.x, accy = us.y;                    // self-loop term

    int e = beg;
    for (; e + 8 <= end; e += 8) {
        int s0 = __builtin_nontemporal_load(&col[e + 0]);
        int s1 = __builtin_nontemporal_load(&col[e + 1]);
        int s2 = __builtin_nontemporal_load(&col[e + 2]);
        int s3 = __builtin_nontemporal_load(&col[e + 3]);
        int s4 = __builtin_nontemporal_load(&col[e + 4]);
        int s5 = __builtin_nontemporal_load(&col[e + 5]);
        int s6 = __builtin_nontemporal_load(&col[e + 6]);
        int s7 = __builtin_nontemporal_load(&col[e + 7]);
        uint b0 = uin[(size_t)s0 * 64 + lane];
        uint b1 = uin[(size_t)s1 * 64 + lane];
        uint b2 = uin[(size_t)s2 * 64 + lane];
        uint b3 = uin[(size_t)s3 * 64 + lane];
        uint b4 = uin[(size_t)s4 * 64 + lane];
        uint b5 = uin[(size_t)s5 * 64 + lane];
        uint b6 = uin[(size_t)s6 * 64 + lane];
        uint b7 = uin[(size_t)s7 * 64 + lane];
        float2 a0 = bf2_to_f2(b0), a1 = bf2_to_f2(b1);
        float2 a2 = bf2_to_f2(b2), a3 = bf2_to_f2(b3);
        float2 a4 = bf2_to_f2(b4), a5 = bf2_to_f2(b5);
        float2 a6 = bf2_to_f2(b6), a7 = bf2_to_f2(b7);
        accx += ((a0.x + a1.x) + (a2.x + a3.x)) + ((a4.x + a5.x) + (a6.x + a7.x));
        accy += ((a0.y + a1.y) + (a2.y + a3.y)) + ((a4.y + a5.y) + (a6.y + a7.y));
    }
    if (e + 4 <= end) {
        int s0 = __builtin_nontemporal_load(&col[e + 0]);
        int s1 = __builtin_nontemporal_load(&col[e + 1]);
        int s2 = __builtin_nontemporal_load(&col[e + 2]);
        int s3 = __builtin_nontemporal_load(&col[e + 3]);
        uint b0 = uin[(size_t)s0 * 64 + lane];
        uint b1 = uin[(size_t)s1 * 64 + lane];
        uint b2 = uin[(size_t)s2 * 64 + lane];
        uint b3 = uin[(size_t)s3 * 64 + lane];
        float2 a0 = bf2_to_f2(b0), a1 = bf2_to_f2(b1);
        float2 a2 = bf2_to_f2(b2), a3 = bf2_to_f2(b3);
        accx += (a0.x + a1.x) + (a2.x + a3.x);
        accy += (a0.y + a1.y) + (a2.y + a3.y);
        e += 4;
    }
    if (e + 2 <= end) {
        int s0 = __builtin_nontemporal_load(&col[e + 0]);
        int s1 = __builtin_nontemporal_load(&col[e + 1]);
        uint b0 = uin[(size_t)s0 * 64 + lane];
        uint b1 = uin[(size_t)s1 * 64 + lane];
        float2 a0 = bf2_to_f2(b0), a1 = bf2_to_f2(b1);
        accx += a0.x + a1.x;
        accy += a0.y + a1.y;
        e += 2;
    }
    if (e < end) {
        int s0 = __builtin_nontemporal_load(&col[e]);
        uint b0 = uin[(size_t)s0 * 64 + lane];
        float2 a0 = bf2_to_f2(b0);
        accx += a0.x;
        accy += a0.y;
    }
    float2 uz = bf2_to_f2(uzv);
    float ox = w * accx + 0.1f * uz.x;
    float oy = w * accy + 0.1f * uz.y;
    __builtin_nontemporal_store(f2_to_bf2(ox, oy), &uout[self]);
}

extern "C" void kernel_launch(void* const* d_in, const int* in_sizes, int n_in,
                              void* d_out, int out_size, void* d_ws, size_t ws_size,
                              hipStream_t stream) {
    (void)in_sizes; (void)n_in; (void)out_size; (void)ws_size;
    const float* x  = (const float*)d_in[0];
    const int*   ei = (const int*)d_in[1];
    const float* W1 = (const float*)d_in[2];
    const float* b1 = (const float*)d_in[3];
    const float* W2 = (const float*)d_in[4];
    const float* b2 = (const float*)d_in[5];
    float* out = (float*)d_out;

    char* ws = (char*)d_ws;
    size_t off = 0;
    auto alloc = [&](size_t bytes) -> void* {
        void* p = ws + off;
        off += (bytes + 255) & ~(size_t)255;
        return p;
    };
    uint*  u0   = (uint*)alloc(sizeof(uint) * (size_t)N_NODES * 64);   // bf16x2 rows
    uint*  uA   = (uint*)alloc(sizeof(uint) * (size_t)N_NODES * 64);
    uint*  uB   = (uint*)alloc(sizeof(uint) * (size_t)N_NODES * 64);
    int*   col  = (int*)alloc(sizeof(int) * N_EDGES);
    int*   pos  = (int*)alloc(sizeof(int) * N_EDGES);
    int*   rp   = (int*)alloc(sizeof(int) * (N_NODES + 1));
    int*   cnt  = (int*)alloc(sizeof(int) * N_NODES);
    float* dinv = (float*)alloc(sizeof(float) * N_NODES);
    float* dsq  = (float*)alloc(sizeof(float) * N_NODES);
    int*   bsum = (int*)alloc(sizeof(int) * SCAN_NB);
    int*   boff = (int*)alloc(sizeof(int) * SCAN_NB);

    hipMemsetAsync(cnt, 0, sizeof(int) * N_NODES, stream);

    k_countpos<<<(N_EDGES / 4 + 255) / 256, 256, 0, stream>>>(ei, cnt, pos);
    k_scan1<<<SCAN_NB, SCAN_T, 0, stream>>>(cnt, rp, bsum, dinv, dsq);
    k_scan2<<<1, SCAN_T, 0, stream>>>(bsum, boff, rp);
    k_scan3<<<SCAN_NB, SCAN_T, 0, stream>>>(rp, boff);
    {
        dim3 g(NZONE, FECH);
        k_fill2<<<g, 256, 0, stream>>>(ei, rp, pos, col);
    }

    k_gemm1<<<N_NODES / 32, 256, 0, stream>>>(x, W1, b1, dinv, u0);

    const uint* uin = u0;
    uint* uout = uA;
    for (int k = 0; k < KSTEPS; ++k) {
        k_step<<<N_NODES / 4, 256, 0, stream>>>(uin, u0, uout, col, rp, dinv);
        uin = uout;
        uout = (uout == uA) ? uB : uA;
    }
    k_gemm2<<<N_NODES / 32, 256, 0, stream>>>(uin, W2, b2, dsq, out);
}